// Round 1
// baseline (3653.907 us; speedup 1.0000x reference)
//
#include <hip/hip_runtime.h>

#define NN 100000
#define NE 1600000
#define HF 128
#define INF 16
#define NLAYERS 19

static inline int idiv(int a, int b) { return (a + b - 1) / b; }

__device__ __forceinline__ float leaky(float v) { return (v >= 0.f) ? v : 0.01f * v; }

// ---------------- preprocessing ----------------

__global__ __launch_bounds__(256) void k_degrees(const int* __restrict__ src, const int* __restrict__ dst,
                                                 int* __restrict__ dout, int* __restrict__ din, int e) {
  int i = blockIdx.x * 256 + threadIdx.x;
  if (i < e) {
    atomicAdd(&dout[src[i]], 1);
    atomicAdd(&din[dst[i]], 1);
  }
}

__global__ __launch_bounds__(256) void k_norms(const int* __restrict__ dout, const int* __restrict__ din,
                                               float* __restrict__ iso, float* __restrict__ isi, int n) {
  int i = blockIdx.x * 256 + threadIdx.x;
  if (i < n) {
    iso[i] = rsqrtf((float)(dout[i] > 1 ? dout[i] : 1));
    isi[i] = rsqrtf((float)(din[i] > 1 ? din[i] : 1));
  }
}

// single-block exclusive scan of counts -> row_ptr (wave-scan based, ~8us one-time)
__global__ __launch_bounds__(1024) void k_scan(const int* __restrict__ cnt, int* __restrict__ rp, int n) {
  __shared__ int wsum[16];
  const int tid = threadIdx.x;
  const int lane = tid & 63;
  const int wid = tid >> 6;
  int carry = 0;
  for (int base = 0; base < n; base += 1024) {
    int i = base + tid;
    int v = (i < n) ? cnt[i] : 0;
    int x = v;
#pragma unroll
    for (int off = 1; off < 64; off <<= 1) {
      int t = __shfl_up(x, off, 64);
      if (lane >= off) x += t;
    }
    if (lane == 63) wsum[wid] = x;
    __syncthreads();
    if (wid == 0) {
      int s = (lane < 16) ? wsum[lane] : 0;
#pragma unroll
      for (int off = 1; off < 16; off <<= 1) {
        int t = __shfl_up(s, off, 64);
        if (lane >= off) s += t;
      }
      if (lane < 16) wsum[lane] = s;
    }
    __syncthreads();
    int woff = (wid > 0) ? wsum[wid - 1] : 0;
    if (i < n) rp[i] = carry + woff + x - v;
    carry += wsum[15];
    __syncthreads();
  }
  if (tid == 0) rp[n] = carry;
}

__global__ __launch_bounds__(256) void k_build(const int* __restrict__ src, const int* __restrict__ dst,
                                               const float* __restrict__ ew, const float* __restrict__ iso,
                                               const float* __restrict__ isi, const int* __restrict__ rp,
                                               int* __restrict__ cursor, int* __restrict__ col,
                                               float* __restrict__ val, int e) {
  int i = blockIdx.x * 256 + threadIdx.x;
  if (i < e) {
    int s = src[i], d = dst[i];
    int pos = rp[d] + atomicAdd(&cursor[d], 1);
    col[pos] = s;
    val[pos] = ew[i] * iso[s] * isi[d];
  }
}

// ---------------- layer 1 (16 feats) ----------------

__global__ __launch_bounds__(256) void k_spmm16(const float* __restrict__ x, const int* __restrict__ rp,
                                                const int* __restrict__ col, const float* __restrict__ val,
                                                float* __restrict__ agg16, int n) {
  int t = blockIdx.x * 256 + threadIdx.x;
  int node = t >> 4, f = t & 15;
  if (node >= n) return;
  int e = rp[node], end = rp[node + 1];
  float a = 0.f;
  for (; e < end; ++e) a = fmaf(val[e], x[(size_t)col[e] * INF + f], a);
  agg16[(size_t)node * INF + f] = a;
}

__global__ __launch_bounds__(256) void k_gemm16(const float* __restrict__ agg16, const float* __restrict__ W1,
                                                const float* __restrict__ b1, float* __restrict__ h, int n) {
  __shared__ float W1s[INF * HF];
  int tid = threadIdx.x;
  {
    float4* d4 = reinterpret_cast<float4*>(W1s);
    const float4* s4 = reinterpret_cast<const float4*>(W1);
    d4[tid] = s4[tid];
    d4[tid + 256] = s4[tid + 256];
  }
  __syncthreads();
  int t = blockIdx.x * 256 + tid;
  int node = t >> 7, c = t & 127;
  if (node >= n) return;
  const float* ar = agg16 + (size_t)node * INF;
  float4 a0 = *reinterpret_cast<const float4*>(ar);
  float4 a1 = *reinterpret_cast<const float4*>(ar + 4);
  float4 a2 = *reinterpret_cast<const float4*>(ar + 8);
  float4 a3 = *reinterpret_cast<const float4*>(ar + 12);
  float av[16] = {a0.x, a0.y, a0.z, a0.w, a1.x, a1.y, a1.z, a1.w,
                  a2.x, a2.y, a2.z, a2.w, a3.x, a3.y, a3.z, a3.w};
  float a = b1[c];
#pragma unroll
  for (int f = 0; f < INF; ++f) a = fmaf(av[f], W1s[f * HF + c], a);
  h[(size_t)t] = leaky(a);
}

// ---------------- hidden layers ----------------

// wave-per-node aggregation: lane holds feature lane and lane+64
__global__ __launch_bounds__(256) void k_spmm(const float* __restrict__ h, const int* __restrict__ rp,
                                              const int* __restrict__ col, const float* __restrict__ val,
                                              float* __restrict__ agg, int n) {
  int lane = threadIdx.x & 63;
  int node = __builtin_amdgcn_readfirstlane(blockIdx.x * 4 + (threadIdx.x >> 6));
  if (node >= n) return;
  int beg = rp[node], end = rp[node + 1];
  float a0 = 0.f, a1 = 0.f;
  int e = beg;
  for (; e + 2 <= end; e += 2) {
    int s0 = col[e], s1 = col[e + 1];
    float v0 = val[e], v1 = val[e + 1];
    const float* p0 = h + (size_t)s0 * HF + lane;
    const float* p1 = h + (size_t)s1 * HF + lane;
    float x00 = p0[0], x01 = p0[64];
    float x10 = p1[0], x11 = p1[64];
    a0 = fmaf(v0, x00, a0);
    a1 = fmaf(v0, x01, a1);
    a0 = fmaf(v1, x10, a0);
    a1 = fmaf(v1, x11, a1);
  }
  if (e < end) {
    int s0 = col[e];
    float v0 = val[e];
    const float* p0 = h + (size_t)s0 * HF + lane;
    a0 = fmaf(v0, p0[0], a0);
    a1 = fmaf(v0, p0[64], a1);
  }
  agg[(size_t)node * HF + lane] = a0;
  agg[(size_t)node * HF + 64 + lane] = a1;
}

// fp32 register-tiled GEMM: 128 nodes x 128 cols per block, 8x8 per thread, K-chunk 32
__global__ __launch_bounds__(256) void k_gemm(const float* __restrict__ A, const float* __restrict__ W,
                                              const float* __restrict__ bias, float* __restrict__ out, int n) {
  __shared__ float As[32][132];  // transposed A chunk [k][node], pad to 132
  __shared__ float Ws[32][HF];
  const int tid = threadIdx.x;
  const int n0 = blockIdx.x * 128;
  const int ty = tid >> 4;  // node octet 0..15
  const int tx = tid & 15;  // col octet 0..15
  float acc[8][8];
#pragma unroll
  for (int i = 0; i < 8; i++)
#pragma unroll
    for (int j = 0; j < 8; j++) acc[i][j] = 0.f;

  for (int kc = 0; kc < HF; kc += 32) {
    {
      int kq = (tid & 7) * 4;
      int nl = tid >> 3;
#pragma unroll
      for (int p = 0; p < 4; ++p) {
        int nn = nl + p * 32;
        int ng = n0 + nn;
        float4 v = make_float4(0.f, 0.f, 0.f, 0.f);
        if (ng < n) v = *reinterpret_cast<const float4*>(A + (size_t)ng * HF + kc + kq);
        As[kq + 0][nn] = v.x;
        As[kq + 1][nn] = v.y;
        As[kq + 2][nn] = v.z;
        As[kq + 3][nn] = v.w;
      }
    }
    {
      int c4 = (tid & 31) * 4;
      int r = tid >> 5;
#pragma unroll
      for (int p = 0; p < 4; ++p) {
        int rr = r + p * 8;
        *reinterpret_cast<float4*>(&Ws[rr][c4]) =
            *reinterpret_cast<const float4*>(W + (size_t)(kc + rr) * HF + c4);
      }
    }
    __syncthreads();
#pragma unroll
    for (int k = 0; k < 32; ++k) {
      float4 a0 = *reinterpret_cast<const float4*>(&As[k][ty * 8]);
      float4 a1 = *reinterpret_cast<const float4*>(&As[k][ty * 8 + 4]);
      float4 w0 = *reinterpret_cast<const float4*>(&Ws[k][tx * 8]);
      float4 w1 = *reinterpret_cast<const float4*>(&Ws[k][tx * 8 + 4]);
      float a[8] = {a0.x, a0.y, a0.z, a0.w, a1.x, a1.y, a1.z, a1.w};
      float w[8] = {w0.x, w0.y, w0.z, w0.w, w1.x, w1.y, w1.z, w1.w};
#pragma unroll
      for (int i = 0; i < 8; i++)
#pragma unroll
        for (int j = 0; j < 8; j++) acc[i][j] = fmaf(a[i], w[j], acc[i][j]);
    }
    __syncthreads();
  }
  float bb[8];
#pragma unroll
  for (int j = 0; j < 8; j++) bb[j] = bias[tx * 8 + j];
#pragma unroll
  for (int i = 0; i < 8; i++) {
    int ng = n0 + ty * 8 + i;
    if (ng < n) {
      float o[8];
#pragma unroll
      for (int j = 0; j < 8; j++) o[j] = leaky(acc[i][j] + bb[j]);
      float4* dst4 = reinterpret_cast<float4*>(out + (size_t)ng * HF + tx * 8);
      dst4[0] = make_float4(o[0], o[1], o[2], o[3]);
      dst4[1] = make_float4(o[4], o[5], o[6], o[7]);
    }
  }
}

// ---------------- head ----------------

__global__ __launch_bounds__(256) void k_head(const float* __restrict__ h, const float* __restrict__ fcW,
                                              const float* __restrict__ fcb, float* __restrict__ out, int n) {
  int gw = (blockIdx.x * 256 + threadIdx.x) >> 6;
  int lane = threadIdx.x & 63;
  int node = gw * 8 + (lane >> 3);
  int part = lane & 7;
  float a0 = 0.f, a1 = 0.f, a2 = 0.f, a3 = 0.f;
  if (node < n) {
    const float* hp = h + (size_t)node * HF + part * 16;
#pragma unroll
    for (int i = 0; i < 16; i++) {
      float xv = hp[i];
      float4 wk = *reinterpret_cast<const float4*>(fcW + (part * 16 + i) * 4);
      a0 = fmaf(xv, wk.x, a0);
      a1 = fmaf(xv, wk.y, a1);
      a2 = fmaf(xv, wk.z, a2);
      a3 = fmaf(xv, wk.w, a3);
    }
  }
#pragma unroll
  for (int m = 1; m < 8; m <<= 1) {
    a0 += __shfl_xor(a0, m, 64);
    a1 += __shfl_xor(a1, m, 64);
    a2 += __shfl_xor(a2, m, 64);
    a3 += __shfl_xor(a3, m, 64);
  }
  if (part == 0 && node < n) {
    float4 o = make_float4(a0 + fcb[0], a1 + fcb[1], a2 + fcb[2], a3 + fcb[3]);
    *reinterpret_cast<float4*>(out + (size_t)node * 4) = o;
  }
}

// ---------------- launch ----------------

extern "C" void kernel_launch(void* const* d_in, const int* in_sizes, int n_in,
                              void* d_out, int out_size, void* d_ws, size_t ws_size,
                              hipStream_t stream) {
  const float* x = (const float*)d_in[0];
  const float* ew = (const float*)d_in[1];
  const int* src = (const int*)d_in[2];
  const int* dst = (const int*)d_in[3];
  const float* W1 = (const float*)d_in[4];
  const float* b1 = (const float*)d_in[5];
  const float* Wst = (const float*)d_in[6];
  const float* bst = (const float*)d_in[7];
  const float* fcW = (const float*)d_in[8];
  const float* fcb = (const float*)d_in[9];
  float* out = (float*)d_out;

  const int n = NN, e = NE;
  char* w = (char*)d_ws;
  size_t off = 0;
  auto alloc = [&](size_t bytes) {
    void* p = w + off;
    off += (bytes + 511) & ~(size_t)511;
    return p;
  };
  int* dout = (int*)alloc((size_t)n * 4);
  int* din = (int*)alloc((size_t)n * 4);
  float* iso = (float*)alloc((size_t)n * 4);
  float* isi = (float*)alloc((size_t)n * 4);
  int* rp = (int*)alloc((size_t)(n + 1) * 4);
  int* cursor = (int*)alloc((size_t)n * 4);
  int* col = (int*)alloc((size_t)e * 4);
  float* val = (float*)alloc((size_t)e * 4);
  float* h = (float*)alloc((size_t)n * HF * 4);
  float* agg = (float*)alloc((size_t)n * HF * 4);
  float* agg16 = agg;  // reuse

  hipMemsetAsync(dout, 0, (size_t)n * 4, stream);
  hipMemsetAsync(din, 0, (size_t)n * 4, stream);
  hipMemsetAsync(cursor, 0, (size_t)n * 4, stream);

  k_degrees<<<idiv(e, 256), 256, 0, stream>>>(src, dst, dout, din, e);
  k_norms<<<idiv(n, 256), 256, 0, stream>>>(dout, din, iso, isi, n);
  k_scan<<<1, 1024, 0, stream>>>(din, rp, n);
  k_build<<<idiv(e, 256), 256, 0, stream>>>(src, dst, ew, iso, isi, rp, cursor, col, val, e);

  k_spmm16<<<idiv(n * INF, 256), 256, 0, stream>>>(x, rp, col, val, agg16, n);
  k_gemm16<<<idiv(n * HF, 256), 256, 0, stream>>>(agg16, W1, b1, h, n);

  for (int l = 0; l < NLAYERS; ++l) {
    k_spmm<<<idiv(n, 4), 256, 0, stream>>>(h, rp, col, val, agg, n);
    k_gemm<<<idiv(n, 128), 256, 0, stream>>>(agg, Wst + (size_t)l * HF * HF, bst + (size_t)l * HF, h, n);
  }
  k_head<<<idiv(n * 8, 256), 256, 0, stream>>>(h, fcW, fcb, out, n);
}

// Round 2
// 3651.608 us; speedup vs baseline: 1.0006x; 1.0006x over previous
//
#include <hip/hip_runtime.h>

#define NN 100000
#define NE 1600000
#define HF 128
#define INF 16
#define NLAYERS 19

static inline int idiv(int a, int b) { return (a + b - 1) / b; }

__device__ __forceinline__ float leaky(float v) { return (v >= 0.f) ? v : 0.01f * v; }

// ---------------- preprocessing ----------------

__global__ __launch_bounds__(256) void k_degrees(const int* __restrict__ src, const int* __restrict__ dst,
                                                 int* __restrict__ dout, int* __restrict__ din, int e) {
  int i = blockIdx.x * 256 + threadIdx.x;
  if (i < e) {
    atomicAdd(&dout[src[i]], 1);
    atomicAdd(&din[dst[i]], 1);
  }
}

__global__ __launch_bounds__(256) void k_norms(const int* __restrict__ dout, const int* __restrict__ din,
                                               float* __restrict__ iso, float* __restrict__ isi, int n) {
  int i = blockIdx.x * 256 + threadIdx.x;
  if (i < n) {
    iso[i] = rsqrtf((float)(dout[i] > 1 ? dout[i] : 1));
    isi[i] = rsqrtf((float)(din[i] > 1 ? din[i] : 1));
  }
}

// single-block exclusive scan of counts -> row_ptr (wave-scan based, ~8us one-time)
__global__ __launch_bounds__(1024) void k_scan(const int* __restrict__ cnt, int* __restrict__ rp, int n) {
  __shared__ int wsum[16];
  const int tid = threadIdx.x;
  const int lane = tid & 63;
  const int wid = tid >> 6;
  int carry = 0;
  for (int base = 0; base < n; base += 1024) {
    int i = base + tid;
    int v = (i < n) ? cnt[i] : 0;
    int x = v;
#pragma unroll
    for (int off = 1; off < 64; off <<= 1) {
      int t = __shfl_up(x, off, 64);
      if (lane >= off) x += t;
    }
    if (lane == 63) wsum[wid] = x;
    __syncthreads();
    if (wid == 0) {
      int s = (lane < 16) ? wsum[lane] : 0;
#pragma unroll
      for (int off = 1; off < 16; off <<= 1) {
        int t = __shfl_up(s, off, 64);
        if (lane >= off) s += t;
      }
      if (lane < 16) wsum[lane] = s;
    }
    __syncthreads();
    int woff = (wid > 0) ? wsum[wid - 1] : 0;
    if (i < n) rp[i] = carry + woff + x - v;
    carry += wsum[15];
    __syncthreads();
  }
  if (tid == 0) rp[n] = carry;
}

__global__ __launch_bounds__(256) void k_build(const int* __restrict__ src, const int* __restrict__ dst,
                                               const float* __restrict__ ew, const float* __restrict__ iso,
                                               const float* __restrict__ isi, const int* __restrict__ rp,
                                               int* __restrict__ cursor, int* __restrict__ col,
                                               float* __restrict__ val, int e) {
  int i = blockIdx.x * 256 + threadIdx.x;
  if (i < e) {
    int s = src[i], d = dst[i];
    int pos = rp[d] + atomicAdd(&cursor[d], 1);
    col[pos] = s;
    val[pos] = ew[i] * iso[s] * isi[d];
  }
}

// ---------------- layer 1 (16 feats) ----------------

__global__ __launch_bounds__(256) void k_spmm16(const float* __restrict__ x, const int* __restrict__ rp,
                                                const int* __restrict__ col, const float* __restrict__ val,
                                                float* __restrict__ agg16, int n) {
  int t = blockIdx.x * 256 + threadIdx.x;
  int node = t >> 4, f = t & 15;
  if (node >= n) return;
  int e = rp[node], end = rp[node + 1];
  float a = 0.f;
  for (; e < end; ++e) a = fmaf(val[e], x[(size_t)col[e] * INF + f], a);
  agg16[(size_t)node * INF + f] = a;
}

__global__ __launch_bounds__(256) void k_gemm16(const float* __restrict__ agg16, const float* __restrict__ W1,
                                                const float* __restrict__ b1, float* __restrict__ h, int n) {
  __shared__ float W1s[INF * HF];
  int tid = threadIdx.x;
  {
    float4* d4 = reinterpret_cast<float4*>(W1s);
    const float4* s4 = reinterpret_cast<const float4*>(W1);
    d4[tid] = s4[tid];
    d4[tid + 256] = s4[tid + 256];
  }
  __syncthreads();
  int t = blockIdx.x * 256 + tid;
  int node = t >> 7, c = t & 127;
  if (node >= n) return;
  const float* ar = agg16 + (size_t)node * INF;
  float4 a0 = *reinterpret_cast<const float4*>(ar);
  float4 a1 = *reinterpret_cast<const float4*>(ar + 4);
  float4 a2 = *reinterpret_cast<const float4*>(ar + 8);
  float4 a3 = *reinterpret_cast<const float4*>(ar + 12);
  float av[16] = {a0.x, a0.y, a0.z, a0.w, a1.x, a1.y, a1.z, a1.w,
                  a2.x, a2.y, a2.z, a2.w, a3.x, a3.y, a3.z, a3.w};
  float a = b1[c];
#pragma unroll
  for (int f = 0; f < INF; ++f) a = fmaf(av[f], W1s[f * HF + c], a);
  h[(size_t)t] = leaky(a);
}

// ---------------- hidden layers ----------------

// wave-per-node aggregation: lane holds feature lane and lane+64
__global__ __launch_bounds__(256) void k_spmm(const float* __restrict__ h, const int* __restrict__ rp,
                                              const int* __restrict__ col, const float* __restrict__ val,
                                              float* __restrict__ agg, int n) {
  int lane = threadIdx.x & 63;
  int node = __builtin_amdgcn_readfirstlane(blockIdx.x * 4 + (threadIdx.x >> 6));
  if (node >= n) return;
  int beg = rp[node], end = rp[node + 1];
  float a0 = 0.f, a1 = 0.f;
  int e = beg;
  for (; e + 2 <= end; e += 2) {
    int s0 = col[e], s1 = col[e + 1];
    float v0 = val[e], v1 = val[e + 1];
    const float* p0 = h + (size_t)s0 * HF + lane;
    const float* p1 = h + (size_t)s1 * HF + lane;
    float x00 = p0[0], x01 = p0[64];
    float x10 = p1[0], x11 = p1[64];
    a0 = fmaf(v0, x00, a0);
    a1 = fmaf(v0, x01, a1);
    a0 = fmaf(v1, x10, a0);
    a1 = fmaf(v1, x11, a1);
  }
  if (e < end) {
    int s0 = col[e];
    float v0 = val[e];
    const float* p0 = h + (size_t)s0 * HF + lane;
    a0 = fmaf(v0, p0[0], a0);
    a1 = fmaf(v0, p0[64], a1);
  }
  agg[(size_t)node * HF + lane] = a0;
  agg[(size_t)node * HF + 64 + lane] = a1;
}

// fp32 register-tiled GEMM: 128 nodes x 128 cols per block, 8x8 per thread, K-chunk 32
__global__ __launch_bounds__(256) void k_gemm(const float* __restrict__ A, const float* __restrict__ W,
                                              const float* __restrict__ bias, float* __restrict__ out, int n) {
  __shared__ float As[32][132];  // transposed A chunk [k][node], pad to 132
  __shared__ float Ws[32][HF];
  const int tid = threadIdx.x;
  const int n0 = blockIdx.x * 128;
  const int ty = tid >> 4;  // node octet 0..15
  const int tx = tid & 15;  // col octet 0..15
  float acc[8][8];
#pragma unroll
  for (int i = 0; i < 8; i++)
#pragma unroll
    for (int j = 0; j < 8; j++) acc[i][j] = 0.f;

  for (int kc = 0; kc < HF; kc += 32) {
    {
      int kq = (tid & 7) * 4;
      int nl = tid >> 3;
#pragma unroll
      for (int p = 0; p < 4; ++p) {
        int nn = nl + p * 32;
        int ng = n0 + nn;
        float4 v = make_float4(0.f, 0.f, 0.f, 0.f);
        if (ng < n) v = *reinterpret_cast<const float4*>(A + (size_t)ng * HF + kc + kq);
        As[kq + 0][nn] = v.x;
        As[kq + 1][nn] = v.y;
        As[kq + 2][nn] = v.z;
        As[kq + 3][nn] = v.w;
      }
    }
    {
      int c4 = (tid & 31) * 4;
      int r = tid >> 5;
#pragma unroll
      for (int p = 0; p < 4; ++p) {
        int rr = r + p * 8;
        *reinterpret_cast<float4*>(&Ws[rr][c4]) =
            *reinterpret_cast<const float4*>(W + (size_t)(kc + rr) * HF + c4);
      }
    }
    __syncthreads();
#pragma unroll
    for (int k = 0; k < 32; ++k) {
      float4 a0 = *reinterpret_cast<const float4*>(&As[k][ty * 8]);
      float4 a1 = *reinterpret_cast<const float4*>(&As[k][ty * 8 + 4]);
      float4 w0 = *reinterpret_cast<const float4*>(&Ws[k][tx * 8]);
      float4 w1 = *reinterpret_cast<const float4*>(&Ws[k][tx * 8 + 4]);
      float a[8] = {a0.x, a0.y, a0.z, a0.w, a1.x, a1.y, a1.z, a1.w};
      float w[8] = {w0.x, w0.y, w0.z, w0.w, w1.x, w1.y, w1.z, w1.w};
#pragma unroll
      for (int i = 0; i < 8; i++)
#pragma unroll
        for (int j = 0; j < 8; j++) acc[i][j] = fmaf(a[i], w[j], acc[i][j]);
    }
    __syncthreads();
  }
  float bb[8];
#pragma unroll
  for (int j = 0; j < 8; j++) bb[j] = bias[tx * 8 + j];
#pragma unroll
  for (int i = 0; i < 8; i++) {
    int ng = n0 + ty * 8 + i;
    if (ng < n) {
      float o[8];
#pragma unroll
      for (int j = 0; j < 8; j++) o[j] = leaky(acc[i][j] + bb[j]);
      float4* dst4 = reinterpret_cast<float4*>(out + (size_t)ng * HF + tx * 8);
      dst4[0] = make_float4(o[0], o[1], o[2], o[3]);
      dst4[1] = make_float4(o[4], o[5], o[6], o[7]);
    }
  }
}

// ---------------- head ----------------

__global__ __launch_bounds__(256) void k_head(const float* __restrict__ h, const float* __restrict__ fcW,
                                              const float* __restrict__ fcb, float* __restrict__ out, int n) {
  int gw = (blockIdx.x * 256 + threadIdx.x) >> 6;
  int lane = threadIdx.x & 63;
  int node = gw * 8 + (lane >> 3);
  int part = lane & 7;
  float a0 = 0.f, a1 = 0.f, a2 = 0.f, a3 = 0.f;
  if (node < n) {
    const float* hp = h + (size_t)node * HF + part * 16;
#pragma unroll
    for (int i = 0; i < 16; i++) {
      float xv = hp[i];
      float4 wk = *reinterpret_cast<const float4*>(fcW + (part * 16 + i) * 4);
      a0 = fmaf(xv, wk.x, a0);
      a1 = fmaf(xv, wk.y, a1);
      a2 = fmaf(xv, wk.z, a2);
      a3 = fmaf(xv, wk.w, a3);
    }
  }
#pragma unroll
  for (int m = 1; m < 8; m <<= 1) {
    a0 += __shfl_xor(a0, m, 64);
    a1 += __shfl_xor(a1, m, 64);
    a2 += __shfl_xor(a2, m, 64);
    a3 += __shfl_xor(a3, m, 64);
  }
  if (part == 0 && node < n) {
    float4 o = make_float4(a0 + fcb[0], a1 + fcb[1], a2 + fcb[2], a3 + fcb[3]);
    *reinterpret_cast<float4*>(out + (size_t)node * 4) = o;
  }
}

// ---------------- launch ----------------

extern "C" void kernel_launch(void* const* d_in, const int* in_sizes, int n_in,
                              void* d_out, int out_size, void* d_ws, size_t ws_size,
                              hipStream_t stream) {
  const float* x = (const float*)d_in[0];
  const float* ew = (const float*)d_in[1];
  const int* src = (const int*)d_in[2];
  const int* dst = (const int*)d_in[3];
  const float* W1 = (const float*)d_in[4];
  const float* b1 = (const float*)d_in[5];
  const float* Wst = (const float*)d_in[6];
  const float* bst = (const float*)d_in[7];
  const float* fcW = (const float*)d_in[8];
  const float* fcb = (const float*)d_in[9];
  float* out = (float*)d_out;

  const int n = NN, e = NE;
  char* w = (char*)d_ws;
  size_t off = 0;
  auto alloc = [&](size_t bytes) {
    void* p = w + off;
    off += (bytes + 511) & ~(size_t)511;
    return p;
  };
  int* dout = (int*)alloc((size_t)n * 4);
  int* din = (int*)alloc((size_t)n * 4);
  float* iso = (float*)alloc((size_t)n * 4);
  float* isi = (float*)alloc((size_t)n * 4);
  int* rp = (int*)alloc((size_t)(n + 1) * 4);
  int* cursor = (int*)alloc((size_t)n * 4);
  int* col = (int*)alloc((size_t)e * 4);
  float* val = (float*)alloc((size_t)e * 4);
  float* h = (float*)alloc((size_t)n * HF * 4);
  float* agg = (float*)alloc((size_t)n * HF * 4);
  float* agg16 = agg;  // reuse

  hipMemsetAsync(dout, 0, (size_t)n * 4, stream);
  hipMemsetAsync(din, 0, (size_t)n * 4, stream);
  hipMemsetAsync(cursor, 0, (size_t)n * 4, stream);

  k_degrees<<<idiv(e, 256), 256, 0, stream>>>(src, dst, dout, din, e);
  k_norms<<<idiv(n, 256), 256, 0, stream>>>(dout, din, iso, isi, n);
  k_scan<<<1, 1024, 0, stream>>>(din, rp, n);
  k_build<<<idiv(e, 256), 256, 0, stream>>>(src, dst, ew, iso, isi, rp, cursor, col, val, e);

  k_spmm16<<<idiv(n * INF, 256), 256, 0, stream>>>(x, rp, col, val, agg16, n);
  k_gemm16<<<idiv(n * HF, 256), 256, 0, stream>>>(agg16, W1, b1, h, n);

  for (int l = 0; l < NLAYERS; ++l) {
    k_spmm<<<idiv(n, 4), 256, 0, stream>>>(h, rp, col, val, agg, n);
    k_gemm<<<idiv(n, 128), 256, 0, stream>>>(agg, Wst + (size_t)l * HF * HF, bst + (size_t)l * HF, h, n);
  }
  k_head<<<idiv(n * 8, 256), 256, 0, stream>>>(h, fcW, fcb, out, n);
}